// Round 8
// baseline (975.371 us; speedup 1.0000x reference)
//
#include <hip/hip_runtime.h>

#define NN 100000
#define EE 320000

typedef unsigned int uint32;
typedef __attribute__((ext_vector_type(8))) short bf16x8;
typedef __attribute__((ext_vector_type(4))) float f32x4;
typedef __attribute__((ext_vector_type(16))) float f32x16;

__device__ __forceinline__ float4 ld4(const float* p){ return *(const float4*)p; }
__device__ __forceinline__ void st4(float* p, const float4 v){ *(float4*)p = v; }
__device__ __forceinline__ float sigm(float x){ return 1.f/(1.f + expf(-x)); }
__device__ __forceinline__ short f2b(float f){
  union { float f; uint32 u; } v; v.f = f;
  uint32 r = (v.u + 0x7FFFu + ((v.u>>16)&1u)) >> 16;   // RNE
  return (short)r;
}

constexpr int EM_STORE=0, EM_BRELU=1, EM_BNLK=2;

// ---------------------------------------------------------------------------
// Generic fp32 tiled GEMM (node path): 64 rows/block, BK=16, 256 threads.
// ---------------------------------------------------------------------------
template<int K,int NOUT,int EM>
__global__ __launch_bounds__(256) void gemm_k(
    const float* __restrict__ A,
    const float* __restrict__ W, const float* __restrict__ bias,
    const float* __restrict__ bng,
    float* __restrict__ C, int M)
{
  constexpr int CN = NOUT/16;
  __shared__ float As[16][68];
  __shared__ float Ws[16][NOUT];
  const int t  = threadIdx.x;
  const int tx = t & 15, ty = t >> 4;
  const int row0 = blockIdx.x * 64;

  float acc[4][CN];
  #pragma unroll
  for (int i=0;i<4;i++)
    #pragma unroll
    for (int j=0;j<CN;j++) acc[i][j]=0.f;

  const int r_st  = t >> 2;
  const int kq_st = (t & 3) * 4;

  for (int k0=0;k0<K;k0+=16) {
    {
      float4 v = make_float4(0.f,0.f,0.f,0.f);
      const int gr = row0 + r_st;
      if (gr < M) v = ld4(A + (size_t)gr*K + k0 + kq_st);
      As[kq_st+0][r_st]=v.x; As[kq_st+1][r_st]=v.y;
      As[kq_st+2][r_st]=v.z; As[kq_st+3][r_st]=v.w;
    }
    {
      constexpr int C4 = NOUT/4;
      for (int i=t;i<16*C4;i+=256){ int kk=i/C4, c4=(i%C4)*4;
        st4(&Ws[kk][c4], ld4(W + (size_t)(k0+kk)*NOUT + c4)); }
    }
    __syncthreads();
    #pragma unroll
    for (int kk=0;kk<16;kk++){
      float a0,a1,a2,a3;
      { const float4 av = *(const float4*)&As[kk][ty*4]; a0=av.x;a1=av.y;a2=av.z;a3=av.w; }
      float b[CN];
      if constexpr ((CN & 3) == 0) {
        #pragma unroll
        for (int j4=0;j4<CN;j4+=4){
          const float4 bv = *(const float4*)&Ws[kk][tx*CN+j4];
          b[j4]=bv.x;b[j4+1]=bv.y;b[j4+2]=bv.z;b[j4+3]=bv.w; }
      } else {
        #pragma unroll
        for (int j=0;j<CN;j++) b[j]=Ws[kk][tx*CN+j];
      }
      #pragma unroll
      for (int j=0;j<CN;j++){
        acc[0][j]=fmaf(a0,b[j],acc[0][j]);
        acc[1][j]=fmaf(a1,b[j],acc[1][j]);
        acc[2][j]=fmaf(a2,b[j],acc[2][j]);
        acc[3][j]=fmaf(a3,b[j],acc[3][j]);
      }
    }
    __syncthreads();
  }

  float sc[CN], sh[CN];
  if constexpr (EM==EM_BNLK) {
    const float r_ = rsqrtf(1.f + 1e-5f);
    #pragma unroll
    for (int j=0;j<CN;j++){ int c=tx*CN+j; sc[j]=bng[c]*r_; sh[j]=bias[c]; }
  }
  #pragma unroll
  for (int i=0;i<4;i++){
    const int r  = row0 + ty*4+i;
    if (r >= M) continue;
    #pragma unroll
    for (int j=0;j<CN;j++){
      const int c = tx*CN+j;
      float v = acc[i][j];
      if constexpr (EM==EM_BRELU) v = fmaxf(v + bias[c], 0.f);
      else if constexpr (EM==EM_BNLK){ float x = fmaf(v, sc[j], sh[j]); v = (x>0.f)? x : 0.2f*x; }
      C[(size_t)r*NOUT + c] = v;
    }
  }
}

// ---------------------------------------------------------------------------
// CSR build: histogram -> scan -> fill
// ---------------------------------------------------------------------------
__global__ void k_hist(const int* __restrict__ eidx, int* cntS, int* cntD, int E){
  int e = blockIdx.x*256+threadIdx.x; if (e>=E) return;
  atomicAdd(&cntS[eidx[2*e]], 1);
  atomicAdd(&cntD[eidx[2*e+1]], 1);
}
__global__ void k_scan_sum(const int* __restrict__ cnt, int* bsum, int n){
  __shared__ int red[256];
  const int b=blockIdx.x, t=threadIdx.x;
  int s=0;
  for (int i=b*1024+t; i<n && i<(b+1)*1024; i+=256) s += cnt[i];
  red[t]=s; __syncthreads();
  for (int o=128;o;o>>=1){ if(t<o) red[t]+=red[t+o]; __syncthreads(); }
  if (t==0) bsum[b]=red[0];
}
__global__ void k_scan_top(int* bsum, int nb){
  __shared__ int sh[256];
  const int t=threadIdx.x;
  int v=(t<nb)?bsum[t]:0;
  sh[t]=v; __syncthreads();
  for (int o=1;o<256;o<<=1){
    int u=0; if(t>=o) u=sh[t-o];
    __syncthreads();
    sh[t]+=u;
    __syncthreads();
  }
  if (t<nb) bsum[t]=sh[t]-v;
}
__global__ void k_scan_out(const int* __restrict__ cnt, const int* __restrict__ bofs,
                           int* __restrict__ off, int n){
  __shared__ int sh[256];
  const int b=blockIdx.x, t=threadIdx.x;
  const int base=b*1024+t*4;
  int c0=0,c1=0,c2=0,c3=0;
  if(base+0<n)c0=cnt[base+0];
  if(base+1<n)c1=cnt[base+1];
  if(base+2<n)c2=cnt[base+2];
  if(base+3<n)c3=cnt[base+3];
  int s=c0+c1+c2+c3;
  sh[t]=s; __syncthreads();
  int v=s;
  for (int o=1;o<256;o<<=1){
    int u=0; if(t>=o) u=sh[t-o];
    __syncthreads();
    sh[t]+=u;
    __syncthreads();
  }
  const int tofs = sh[t]-v + bofs[b];
  if(base+0<n) off[base+0]=tofs;
  if(base+1<n) off[base+1]=tofs+c0;
  if(base+2<n) off[base+2]=tofs+c0+c1;
  if(base+3<n) off[base+3]=tofs+c0+c1+c2;
}
__global__ void k_copyoff(const int* __restrict__ off, int* __restrict__ cur, int n){
  int i=blockIdx.x*256+threadIdx.x;
  if (i<n) cur[i]=off[i];
}
__global__ void k_setend(int* offS, int* offD, int n, int E){
  if (threadIdx.x==0 && blockIdx.x==0){ offS[n]=E; offD[n]=E; }
}
__global__ void k_fill(const int* __restrict__ eidx, int* curS, int* curD,
                       int* __restrict__ csrS, int* __restrict__ csrD, int E){
  int e=blockIdx.x*256+threadIdx.x; if (e>=E) return;
  const int s=eidx[2*e], d=eidx[2*e+1];
  csrS[atomicAdd(&curS[s],1)] = d;
  csrD[atomicAdd(&curD[d],1)] = s;
}
__global__ void k_dis(const int* __restrict__ cntD, float* __restrict__ dis, int n){
  int i=blockIdx.x*256+threadIdx.x; if(i>=n)return;
  dis[i]=rsqrtf((float)cntD[i]+1.f);
}

// ---------------------------------------------------------------------------
// Wcat = [Wbot | Wd | gcn1W]  (128 x 192 fp32)
// ---------------------------------------------------------------------------
__global__ void k_wprep(const float* __restrict__ eattnW, const float* __restrict__ gcn1W,
                        float* __restrict__ Wcat){
  int idx=blockIdx.x*256+threadIdx.x; if (idx>=128*192) return;
  int k=idx/192, c=idx-k*192;
  float v;
  if (c<64)       v = eattnW[(size_t)(128+k)*64 + c];
  else if (c<128) v = eattnW[(size_t)k*64 + (c-64)] - eattnW[(size_t)(128+k)*64 + (c-64)];
  else            v = gcn1W[(size_t)k*64 + (c-128)];
  Wcat[idx]=v;
}

// ---------------------------------------------------------------------------
// CSR gather-sum
// ---------------------------------------------------------------------------
template<int NC>
__global__ void k_gather(const float* __restrict__ src, int stride, int colbase,
                         const int* __restrict__ off, const int* __restrict__ csr,
                         float* __restrict__ out, int n){
  constexpr int TPN = NC/4;
  const int t=threadIdx.x;
  const int node = blockIdx.x*(256/TPN) + t/TPN; if (node>=n) return;
  const int cq = (t%TPN)*4;
  const int j1=off[node+1];
  float4 acc = make_float4(0.f,0.f,0.f,0.f);
  for (int j=off[node]; j<j1; ++j){
    const float4 v = ld4(src + (size_t)csr[j]*stride + colbase + cq);
    acc.x+=v.x; acc.y+=v.y; acc.z+=v.z; acc.w+=v.w;
  }
  st4(out + (size_t)node*NC + cq, acc);
}

// aei = sigmoid(row*col)
__global__ void k_aei3(const float* __restrict__ TUL, const float* __restrict__ Q,
                       const float* __restrict__ S, const int* __restrict__ cntS,
                       const int* __restrict__ cntD, const float* __restrict__ bias,
                       float* __restrict__ aei, int n){
  int idx=blockIdx.x*256+threadIdx.x; if (idx>=n*16) return;
  const int i=idx>>4, cq=(idx&15)*4;
  const float cS=(float)cntS[i], cD=(float)cntD[i];
  const float iS=1.f/fmaxf(cS,1.f), iD=1.f/fmaxf(cD,1.f);
  const float* tul = TUL + (size_t)i*192;
  const float4 T4=ld4(tul+cq), U4=ld4(tul+64+cq);
  const float4 Q4=ld4(Q+(size_t)i*64+cq), S4=ld4(S+(size_t)i*64+cq), b4=ld4(bias+cq);
  float4 o;
  o.x=sigm(((cS*(U4.x+b4.x)+Q4.x)*iS) * ((cD*(T4.x+b4.x)+S4.x)*iD));
  o.y=sigm(((cS*(U4.y+b4.y)+Q4.y)*iS) * ((cD*(T4.y+b4.y)+S4.y)*iD));
  o.z=sigm(((cS*(U4.z+b4.z)+Q4.z)*iS) * ((cD*(T4.z+b4.z)+S4.z)*iD));
  o.w=sigm(((cS*(U4.w+b4.w)+Q4.w)*iS) * ((cD*(T4.w+b4.w)+S4.w)*iD));
  st4(aei + (size_t)i*64 + cq, o);
}

// GCN aggregate + combine
template<int NC, bool AEI>
__global__ void k_gcnagg(const float* __restrict__ lin, int stride, int colbase,
                         const int* __restrict__ off, const int* __restrict__ csr,
                         const float* __restrict__ dis, const float* __restrict__ aei,
                         const float* __restrict__ bias, float* __restrict__ h, int n){
  constexpr int TPN = NC/4;
  const int t=threadIdx.x;
  const int node = blockIdx.x*(256/TPN) + t/TPN; if (node>=n) return;
  const int cq = (t%TPN)*4;
  const int j1=off[node+1];
  float4 acc = make_float4(0.f,0.f,0.f,0.f);
  for (int j=off[node]; j<j1; ++j){
    const int s=csr[j];
    const float w=dis[s];
    const float4 v = ld4(lin + (size_t)s*stride + colbase + cq);
    acc.x=fmaf(v.x,w,acc.x); acc.y=fmaf(v.y,w,acc.y);
    acc.z=fmaf(v.z,w,acc.z); acc.w=fmaf(v.w,w,acc.w);
  }
  const float dn=dis[node], d2=dn*dn;
  const float4 own=ld4(lin + (size_t)node*stride + colbase + cq), b4=ld4(bias+cq);
  float4 o;
  o.x=fmaxf(fmaf(acc.x,dn,fmaf(own.x,d2,b4.x)),0.f);
  o.y=fmaxf(fmaf(acc.y,dn,fmaf(own.y,d2,b4.y)),0.f);
  o.z=fmaxf(fmaf(acc.z,dn,fmaf(own.z,d2,b4.z)),0.f);
  o.w=fmaxf(fmaf(acc.w,dn,fmaf(own.w,d2,b4.w)),0.f);
  if (AEI){ const float4 m=ld4(aei+(size_t)node*NC+cq); o.x*=m.x;o.y*=m.y;o.z*=m.z;o.w*=m.w; }
  st4(h + (size_t)node*NC + cq, o);
}

// ---------------------------------------------------------------------------
// Weight transpose + cast (+k-rotation): Wt[NP][K] bf16, Wt[n][k] = W[(k+krot)%K][n]
// ---------------------------------------------------------------------------
__global__ void k_twt(const float* __restrict__ W, short* __restrict__ Wt,
                      int K, int N, int NP, int krot){
  int idx = blockIdx.x*256 + threadIdx.x;
  if (idx >= NP*K) return;
  int n = idx / K, k = idx - n*K;
  int ks = k + krot; if (ks >= K) ks -= K;
  Wt[idx] = (n<N)? f2b(W[(size_t)ks*N + n]) : (short)0;
}

// ---------------------------------------------------------------------------
// 32x32x16 MFMA phase: C(128 x NT*32) += As(128 x KTOT bf16) @ Wt^T.
// 256 threads / 4 waves; wave w owns rows [w*32, w*32+32), all NT col-tiles.
// A row = lane&31, k = (lane>>5)*8+j (same k-map as B -> permutation invariant).
// Bs double-buffered per 16-k step; weights prefetched to regs; 1 sync/step.
// ---------------------------------------------------------------------------
template<int KTOT, int NT>
__device__ __forceinline__ void mm32(
    const short* __restrict__ Wt,
    short (*As)[264], short (*Bs)[128][24],
    int t, int lane, int w, f32x16* acc)
{
  constexpr int STEPS = KTOT/16;
  constexpr int NC = NT*32;
  const int lane31 = lane & 31, kh = lane >> 5;
  const int arow = w*32 + lane31;
  const bool act = (t < NC*2);
  const int col = t >> 1, half = t & 1;
  const short* wp = Wt + (size_t)col*KTOT + half*8;
  float4 r;
  if (act){
    r = *(const float4*)wp;
    *(float4*)&Bs[0][col][half*8] = r;
  }
  __syncthreads();
  #pragma unroll
  for (int ks=0; ks<STEPS; ++ks){
    if (act && ks+1<STEPS) r = *(const float4*)(wp + (ks+1)*16);
    const bf16x8 a = *(const bf16x8*)&As[arow][ks*16 + kh*8];
    #pragma unroll
    for (int ct=0; ct<NT; ++ct){
      const bf16x8 b = *(const bf16x8*)&Bs[ks&1][ct*32 + lane31][kh*8];
      acc[ct] = __builtin_amdgcn_mfma_f32_32x32x16_bf16(a, b, acc[ct], 0, 0, 0);
    }
    if (act && ks+1<STEPS) *(float4*)&Bs[(ks+1)&1][col][half*8] = r;
    __syncthreads();
  }
}

// C-row within 32-row tile for accumulator register `reg` (m74/m101 layout)
__device__ __forceinline__ int rowof(int reg, int kh){
  return (reg & 3) + ((reg >> 2) << 3) + (kh << 2);
}

// ---------------------------------------------------------------------------
// Fused edge mega-kernel (bf16 MFMA 32x32x16, 256 thr, 128 edges/block):
//   gate + emlp1(*G) + emlp2 + elin1(BN,leaky) + elin2 -> elog
// ef1/ef2/ex ping-pong inside As; elin1 weights are k-rotated by 128.
// ---------------------------------------------------------------------------
__global__ __launch_bounds__(256) void k_edge(
  const float* __restrict__ nf, const float* __restrict__ ni,
  const int* __restrict__ eidx,
  const short* __restrict__ wt_nred, const float* __restrict__ nredb,
  const short* __restrict__ wt_e1,   const float* __restrict__ e1b,
  const short* __restrict__ wt_e2,   const float* __restrict__ e2b,
  const short* __restrict__ wt_l1,   const float* __restrict__ ebng, const float* __restrict__ ebnb,
  const short* __restrict__ wt_l2,
  float* __restrict__ elog)
{
  __shared__ short As[128][264];     // 67584 B
  __shared__ short Bs[2][128][24];   // 12288 B  (total 79872 -> 2 blocks/CU)
  const int t = threadIdx.x;
  const int lane = t & 63, w = t >> 6;
  const int row0 = blockIdx.x * 128;
  const int lane31 = lane & 31, kh = lane >> 5;

  // staging: 2 threads per edge-row; each handles 128 floats (one concat half)
  const int srow = t >> 1, sseg = t & 1;
  const int s_s = eidx[2*(row0+srow)], s_d = eidx[2*(row0+srow)+1];

  // ---- phase 1: gate, A = concat(ni[s], ni[d]) ----
  {
    const float* src = sseg ? (ni + (size_t)s_d*128) : (ni + (size_t)s_s*128);
    short* dst = &As[srow][sseg*128];
    #pragma unroll
    for (int p=0;p<16;p++){
      float4 u = ld4(src + p*8), v = ld4(src + p*8 + 4);
      bf16x8 o;
      o[0]=f2b(u.x);o[1]=f2b(u.y);o[2]=f2b(u.z);o[3]=f2b(u.w);
      o[4]=f2b(v.x);o[5]=f2b(v.y);o[6]=f2b(v.z);o[7]=f2b(v.w);
      *(bf16x8*)(dst + p*8) = o;
    }
  }
  f32x16 acc[4];
  #pragma unroll
  for (int j=0;j<4;j++) acc[j] = (f32x16)(0.f);
  mm32<256,4>(wt_nred, As, Bs, t, lane, w, acc);

  // gate -> packed bf16 pairs (32 regs)
  uint32 gp[4][8];
  #pragma unroll
  for (int ct=0;ct<4;ct++){
    const float bb = nredb[ct*32 + lane31];
    #pragma unroll
    for (int rq=0;rq<8;rq++){
      const uint32 g0 = (uint32)(unsigned short)f2b(sigm(acc[ct][2*rq]   + bb));
      const uint32 g1 = (uint32)(unsigned short)f2b(sigm(acc[ct][2*rq+1] + bb));
      gp[ct][rq] = g0 | (g1<<16);
    }
  }

  // ---- phase 2: emlp1, A = concat(nf[s], nf[d]-nf[s]) ----
  {
    short* dst = &As[srow][sseg*128];
    #pragma unroll
    for (int p=0;p<16;p++){
      float4 u, v;
      if (sseg == 0){
        u = ld4(nf + (size_t)s_s*128 + p*8);
        v = ld4(nf + (size_t)s_s*128 + p*8 + 4);
      } else {
        float4 ua = ld4(nf + (size_t)s_d*128 + p*8);
        float4 ub = ld4(nf + (size_t)s_s*128 + p*8);
        float4 va = ld4(nf + (size_t)s_d*128 + p*8 + 4);
        float4 vb = ld4(nf + (size_t)s_s*128 + p*8 + 4);
        u.x=ua.x-ub.x; u.y=ua.y-ub.y; u.z=ua.z-ub.z; u.w=ua.w-ub.w;
        v.x=va.x-vb.x; v.y=va.y-vb.y; v.z=va.z-vb.z; v.w=va.w-vb.w;
      }
      bf16x8 o;
      o[0]=f2b(u.x);o[1]=f2b(u.y);o[2]=f2b(u.z);o[3]=f2b(u.w);
      o[4]=f2b(v.x);o[5]=f2b(v.y);o[6]=f2b(v.z);o[7]=f2b(v.w);
      *(bf16x8*)(dst + p*8) = o;
    }
  }
  #pragma unroll
  for (int j=0;j<4;j++) acc[j] = (f32x16)(0.f);
  mm32<256,4>(wt_e1, As, Bs, t, lane, w, acc);

  // ef1 = relu(acc+b)*G -> As cols 0..127
  #pragma unroll
  for (int ct=0;ct<4;ct++){
    const int col = ct*32 + lane31;
    const float bb = e1b[col];
    #pragma unroll
    for (int reg=0;reg<16;reg++){
      const uint32 u = gp[ct][reg>>1];
      const float gv = __uint_as_float((reg&1) ? (u & 0xFFFF0000u) : (u<<16));
      As[w*32 + rowof(reg,kh)][col] = f2b(fmaxf(acc[ct][reg] + bb, 0.f) * gv);
    }
  }

  // ---- phase 3: emlp2 (128 -> 256), two 128-col halves ----
  // half 0 -> As cols 128..255 (ef2 cols 0..127)
  #pragma unroll
  for (int j=0;j<4;j++) acc[j] = (f32x16)(0.f);
  mm32<128,4>(wt_e2, As, Bs, t, lane, w, acc);
  #pragma unroll
  for (int ct=0;ct<4;ct++){
    const int col = ct*32 + lane31;
    const float bb = e2b[col];
    #pragma unroll
    for (int reg=0;reg<16;reg++)
      As[w*32 + rowof(reg,kh)][128+col] = f2b(fmaxf(acc[ct][reg] + bb, 0.f));
  }
  // half 1 (reads ef1 cols 0..127; results -> As cols 0..127 after mm32 done)
  #pragma unroll
  for (int j=0;j<4;j++) acc[j] = (f32x16)(0.f);
  mm32<128,4>(wt_e2 + (size_t)128*128, As, Bs, t, lane, w, acc);
  #pragma unroll
  for (int ct=0;ct<4;ct++){
    const int col = ct*32 + lane31;
    const float bb = e2b[128+col];
    #pragma unroll
    for (int reg=0;reg<16;reg++)
      As[w*32 + rowof(reg,kh)][col] = f2b(fmaxf(acc[ct][reg] + bb, 0.f));
  }

  // ---- phase 4: elin1 (256 -> 128), weights k-rotated to match As layout ----
  #pragma unroll
  for (int j=0;j<4;j++) acc[j] = (f32x16)(0.f);
  mm32<256,4>(wt_l1, As, Bs, t, lane, w, acc);
  {
    const float r_ = rsqrtf(1.f + 1e-5f);
    #pragma unroll
    for (int ct=0;ct<4;ct++){
      const int col = ct*32 + lane31;
      const float sc = ebng[col]*r_, sh = ebnb[col];
      #pragma unroll
      for (int reg=0;reg<16;reg++){
        float x = fmaf(acc[ct][reg], sc, sh);
        As[w*32 + rowof(reg,kh)][col] = f2b((x>0.f)? x : 0.2f*x);
      }
    }
  }

  // ---- phase 5: elin2 (128 -> 27, padded 32) ----
  f32x16 acc5 = (f32x16)(0.f);
  mm32<128,1>(wt_l2, As, Bs, t, lane, w, &acc5);

  // bounce through LDS for coalesced fp32 store
  float* Lb = (float*)&As[0][0];   // [128][28]
  if (lane31 < 27){
    #pragma unroll
    for (int reg=0;reg<16;reg++)
      Lb[(w*32 + rowof(reg,kh))*28 + lane31] = acc5[reg];
  }
  __syncthreads();
  for (int i=t; i<128*27; i+=256){
    int rr = i/27, cc = i - rr*27;
    elog[(size_t)(row0+rr)*27 + cc] = Lb[rr*28 + cc];
  }
}

// ---------------------------- tail kernels --------------------------------
__global__ __launch_bounds__(256) void k_softmax_row(float* __restrict__ x, int M){
  const int wave = threadIdx.x>>6, lane = threadIdx.x&63;
  const int r = blockIdx.x*4 + wave; if (r>=M) return;
  float* p = x + (size_t)r*160;
  float v0 = p[lane], v1 = p[64+lane];
  float v2 = (lane<32)? p[128+lane] : -3.4e38f;
  float m = fmaxf(fmaxf(v0,v1),v2);
  for (int o=32;o;o>>=1) m = fmaxf(m, __shfl_xor(m,o));
  float e0=expf(v0-m), e1=expf(v1-m), e2=(lane<32)?expf(v2-m):0.f;
  float s=e0+e1+e2;
  for (int o=32;o;o>>=1) s += __shfl_xor(s,o);
  float inv = 1.f/s;
  p[lane]=e0*inv; p[64+lane]=e1*inv; if(lane<32)p[128+lane]=e2*inv;
}
__global__ void k_colmax(const float* __restrict__ x, uint32* __restrict__ cmax_u, int E){
  __shared__ float red[8][32];
  const int t=threadIdx.x, col=t&31, seg=t>>5;
  float m = -3.4e38f;
  if (col < 27)
    for (int r = blockIdx.x*8 + seg; r < E; r += gridDim.x*8)
      m = fmaxf(m, x[(size_t)r*27+col]);
  red[seg][col]=m; __syncthreads();
  if (t<32){
    float mm=red[0][t];
    #pragma unroll
    for (int s2=1;s2<8;s2++) mm=fmaxf(mm,red[s2][t]);
    if (t<27){
      uint32 u=__float_as_uint(mm);
      u = (u&0x80000000u)? ~u : (u|0x80000000u);
      atomicMax(&cmax_u[t], u);
    }
  }
}
__global__ void k_colfix(const uint32* __restrict__ cmax_u, float* __restrict__ cmaxf){
  int t=threadIdx.x; if (t>=27) return;
  uint32 u=cmax_u[t];
  cmaxf[t] = (u&0x80000000u)? __uint_as_float(u&0x7FFFFFFFu) : __uint_as_float(~u);
}
__global__ void k_colsum(const float* __restrict__ x, const float* __restrict__ cmaxf,
                         float* __restrict__ csum, int E){
  __shared__ float red[8][32];
  const int t=threadIdx.x, col=t&31, seg=t>>5;
  float s = 0.f;
  if (col < 27){
    const float cm = cmaxf[col];
    for (int r = blockIdx.x*8 + seg; r < E; r += gridDim.x*8)
      s += expf(x[(size_t)r*27+col] - cm);
  }
  red[seg][col]=s; __syncthreads();
  if (t<32){
    float ss=red[0][t];
    #pragma unroll
    for (int s2=1;s2<8;s2++) ss+=red[s2][t];
    if (t<27) atomicAdd(&csum[t], ss);
  }
}
__global__ void k_colnorm(float* __restrict__ x, const float* __restrict__ cmaxf,
                          const float* __restrict__ csum, int E){
  int idx=blockIdx.x*256+threadIdx.x;
  if (idx >= E*27) return;
  int c = idx - (idx/27)*27;
  x[idx] = expf(x[idx]-cmaxf[c]) / csum[c];
}

// ---------------------------------------------------------------------------
extern "C" void kernel_launch(void* const* d_in, const int* in_sizes, int n_in,
                              void* d_out, int out_size, void* d_ws, size_t ws_size,
                              hipStream_t stream)
{
  const float* nf     = (const float*)d_in[0];
  const int*   eidx   = (const int*)  d_in[1];
  const float* gcn1W  = (const float*)d_in[2];
  const float* gcn1b  = (const float*)d_in[3];
  const float* gcn2W  = (const float*)d_in[4];
  const float* gcn2b  = (const float*)d_in[5];
  const float* eattnW = (const float*)d_in[6];
  const float* eattnb = (const float*)d_in[7];
  const float* nattnW = (const float*)d_in[8];
  const float* nattnb = (const float*)d_in[9];
  const float* nredW  = (const float*)d_in[10];
  const float* nredb  = (const float*)d_in[11];
  const float* emlp1W = (const float*)d_in[12];
  const float* emlp1b = (const float*)d_in[13];
  const float* emlp2W = (const float*)d_in[14];
  const float* emlp2b = (const float*)d_in[15];
  const float* nlin1W = (const float*)d_in[16];
  const float* nbng   = (const float*)d_in[17];
  const float* nbnb   = (const float*)d_in[18];
  const float* nlin2W = (const float*)d_in[19];
  const float* elin1W = (const float*)d_in[20];
  const float* ebng   = (const float*)d_in[21];
  const float* ebnb   = (const float*)d_in[22];
  const float* elin2W = (const float*)d_in[23];
  (void)in_sizes; (void)n_in; (void)out_size; (void)ws_size;

  const int N = NN, E = EE;
  float* out  = (float*)d_out;
  float* nlog = out;                       // N*160
  float* elog = out + (size_t)N*160;       // E*27

  // ---- workspace plan (~237 MB) ----
  float* ws   = (float*)d_ws;
  float* h2   = ws;                        // N*128
  float* lin2 = ws + (size_t)N*128;        // N*128 ; Q/S early, niB/nx later
  float* Q    = lin2;                      // N*64
  float* S    = lin2 + (size_t)N*64;       // N*64
  float* niB  = lin2;
  float* nx   = lin2;
  float* TUL  = ws + (size_t)N*256;        // N*192  [T|U|lin1]
  float* h1   = ws + (size_t)N*448;        // N*64
  float* aei  = ws + (size_t)N*512;        // N*64
  float* dis  = ws + (size_t)N*576;        // N
  float* smalls = ws + (size_t)N*577;      // 96
  float* Wcat = smalls + 128;              // 128*192
  int*   ip   = (int*)(Wcat + 24576);
  int* cntS = ip;                          // N
  int* cntD = ip + N;                      // N
  int* offS = ip + 2*N;                    // N+64
  int* offD = ip + 3*N + 64;               // N+64
  int* curS = ip + 4*N + 128;              // N
  int* curD = ip + 5*N + 128;              // N
  int* csrS = ip + 6*N + 128;              // E
  int* csrD = ip + 6*N + 128 + E;          // E
  int* bsum = ip + 6*N + 128 + 2*E;        // 256
  short* wtb  = (short*)(bsum + 256);
  short* wt_nred = wtb;                    // 128*256
  short* wt_e1   = wtb + 32768;
  short* wt_e2   = wtb + 65536;
  short* wt_l1   = wtb + 98304;
  short* wt_l2   = wtb + 131072;           // 32*128

  const int NB1024 = (N + 1023)/1024;      // 98

  // 0. weight prep (wt_l1 k-rotated by 128 to match As ping-pong layout)
  k_twt<<<128,256,0,stream>>>(nredW,  wt_nred, 256, 128, 128, 0);
  k_twt<<<128,256,0,stream>>>(emlp1W, wt_e1,   256, 128, 128, 0);
  k_twt<<<128,256,0,stream>>>(emlp2W, wt_e2,   128, 256, 256, 0);
  k_twt<<<128,256,0,stream>>>(elin1W, wt_l1,   256, 128, 128, 128);
  k_twt<<<16, 256,0,stream>>>(elin2W, wt_l2,   128, 27,  32,  0);
  k_wprep<<<96,256,0,stream>>>(eattnW, gcn1W, Wcat);

  // 1. CSR build (both directions)
  (void)hipMemsetAsync(cntS, 0, 2*(size_t)N*sizeof(int), stream);
  k_hist<<<(E+255)/256,256,0,stream>>>(eidx, cntS, cntD, E);
  k_scan_sum<<<NB1024,256,0,stream>>>(cntS, bsum, N);
  k_scan_top<<<1,256,0,stream>>>(bsum, NB1024);
  k_scan_out<<<NB1024,256,0,stream>>>(cntS, bsum, offS, N);
  k_scan_sum<<<NB1024,256,0,stream>>>(cntD, bsum, N);
  k_scan_top<<<1,256,0,stream>>>(bsum, NB1024);
  k_scan_out<<<NB1024,256,0,stream>>>(cntD, bsum, offD, N);
  k_setend<<<1,64,0,stream>>>(offS, offD, N, E);
  k_copyoff<<<(N+255)/256,256,0,stream>>>(offS, curS, N);
  k_copyoff<<<(N+255)/256,256,0,stream>>>(offD, curD, N);
  k_fill<<<(E+255)/256,256,0,stream>>>(eidx, curS, curD, csrS, csrD, E);
  k_dis<<<(N+255)/256,256,0,stream>>>(cntD, dis, N);

  // 2. TUL = nf @ [Wbot|Wd|gcn1W]
  gemm_k<128,192,EM_STORE><<<(N+63)/64,256,0,stream>>>(nf, Wcat, nullptr, nullptr, TUL, N);

  // 3. eattn segment means via gathers
  k_gather<64><<<(N+15)/16,256,0,stream>>>(TUL, 192, 0,  offS, csrS, Q, N);
  k_gather<64><<<(N+15)/16,256,0,stream>>>(TUL, 192, 64, offD, csrD, S, N);
  k_aei3<<<(N*16+255)/256,256,0,stream>>>(TUL, Q, S, cntS, cntD, eattnb, aei, N);

  // 4. GCN conv 1
  k_gcnagg<64,true><<<(N+15)/16,256,0,stream>>>(TUL, 192, 128, offD, csrD, dis, aei, gcn1b, h1, N);

  // 5. GCN conv 2
  gemm_k<64,128,EM_STORE><<<(N+63)/64,256,0,stream>>>(h1, gcn2W, nullptr, nullptr, lin2, N);
  k_gcnagg<128,false><<<(N+7)/8,256,0,stream>>>(lin2, 128, 0, offD, csrD, dis, nullptr, gcn2b, h2, N);

  // 6. node attention
  gemm_k<128,128,EM_BRELU><<<(N+63)/64,256,0,stream>>>(h2, nattnW, nattnb, nullptr, niB, N);

  // 7. fused edge chain (bf16 MFMA 32x32x16, 2 blocks/CU)
  k_edge<<<E/128,256,0,stream>>>(
      nf, niB, eidx,
      wt_nred, nredb, wt_e1, emlp1b, wt_e2, emlp2b,
      wt_l1, ebng, ebnb, wt_l2, elog);

  // 8. node head
  gemm_k<128,64,EM_BNLK><<<(N+63)/64,256,0,stream>>>(h2, nlin1W, nbnb, nbng, nx, N);
  gemm_k<64,160,EM_STORE><<<(N+63)/64,256,0,stream>>>(nx, nlin2W, nullptr, nullptr, nlog, N);
  k_softmax_row<<<(N+3)/4,256,0,stream>>>(nlog, N);

  // 9. column softmax over E (in place in d_out)
  (void)hipMemsetAsync(smalls, 0, 96*sizeof(float), stream);
  k_colmax<<<1024,256,0,stream>>>(elog, (uint32*)smalls, E);
  k_colfix<<<1,32,0,stream>>>((const uint32*)smalls, smalls+64);
  k_colsum<<<1024,256,0,stream>>>(elog, smalls+64, smalls+32, E);
  k_colnorm<<<(E*27+255)/256,256,0,stream>>>(elog, smalls+64, smalls+32, E);
}